// Round 13
// baseline (441.377 us; speedup 1.0000x reference)
//
#include <hip/hip_runtime.h>

typedef _Float16 v8h __attribute__((ext_vector_type(8)));
typedef float    v4f __attribute__((ext_vector_type(4)));

#define MFMA16(A,B,C) __builtin_amdgcn_mfma_f32_16x16x32_f16((A),(B),(C),0,0,0)

#define RPB 8
#define TT  256
#define HH  64
#define KST 136      // f16 stride per A row: k 0-63 = ha, 64-127 = hb, 8 pad
#define SG  256.0f   // sigmoid index scale (table step 1/256)
#define TG  512.0f   // g-gate tanh index scale (tanh(z)=2*sigma(2z)-1)
#define IOFF 4096.5f // index center + 0.5 NN rounding offset
#define TSC2 -2.88539008f // -2*log2(e): tanh(c)=2*rcp(1+exp2(c*TSC2))-1

// Layer-specialized waves: 512-thr blocks (8 waves), grid 512 = 2 blocks/CU
// = 4 waves/SIMD from independent-mix streams. Waves 0-3: layer0, col slice
// (w&3); waves 4-7: layer1. Dup-read M=16 tile (A rows l15&7): C rows 8-15
// duplicate 0-7, so quads split rows -> every lane: exactly 2 pointwise
// instances, NO selects, no junk. Per-CU totals (gathers/MFMA/pointwise)
// identical to R9; the win is de-convoyed heterogeneous streams. R9 gate
// recipe: all 4 gates NN-LUT, c-tanh via exp2+rcp. Weights per wave type
// halve -> VGPR fits 128 for 4 waves/SIMD.
__global__ __launch_bounds__(512, 4)
void lstm2_kernel(const float* __restrict__ x,     // [4096][256]
                  const float* __restrict__ Wih0,  // [256][1]
                  const float* __restrict__ Whh0,  // [256][64]
                  const float* __restrict__ bih0,
                  const float* __restrict__ bhh0,
                  const float* __restrict__ Wih1,  // [256][64]
                  const float* __restrict__ Whh1,  // [256][64]
                  const float* __restrict__ bih1,
                  const float* __restrict__ bhh1,
                  const float* __restrict__ Wlin,  // [64][64]
                  const float* __restrict__ blin,
                  float* __restrict__ out)         // [4096][64]
{
    __shared__ float xl[TT][RPB];                      // 8 KB
    __shared__ __align__(16) _Float16 hs[2][RPB][KST]; // 4.25 KB
    __shared__ float hbF[RPB][HH];                     // 2 KB
    __shared__ float lut[8192];                        // 32 KB sigma table

    const int tid  = threadIdx.x;
    const int w    = tid >> 6;         // 0..7
    const int l15  = tid & 15;
    const int l7   = tid & 7;          // A-frag row (dup-read)
    const int q    = (tid & 63) >> 4;
    const int row0 = (int)blockIdx.x * RPB;
    const int jj   = (w & 3) * 16 + l15;
    const bool isL0 = (w < 4);
    const int  mr  = (q & 1) * 4;                 // x-init row base (4 rows)
    const int  mb  = (q & 1) * 4 + (q >> 1) * 2;  // my 2 pointwise rows: mb, mb+1
    const int  rr  = (q >> 1) * 2;                // my acc reg indices: rr, rr+1

    for (int idx = tid; idx < RPB * TT; idx += 512) {
        int m = idx & 7, t = idx >> 3;
        xl[t][m] = x[(row0 + m) * TT + t];
    }
    for (int idx = tid; idx < 2 * RPB * KST; idx += 512)
        ((_Float16*)hs)[idx] = (_Float16)0.f;
    for (int i = tid; i < 8192; i += 512)
        lut[i] = 1.0f / (1.0f + __expf(-(i - 4096) * (1.0f / 256.0f)));

    // sigma via nearest-neighbor LUT; f is a pre-scaled index (z*256+4096.5)
    auto lutv = [&](float f) -> float {
        f = __builtin_amdgcn_fmed3f(f, 0.0f, 8191.0f);
        return lut[(int)f];
    };
    // tanh(c) via hardware exp2+rcp (near-exact, no gather)
    auto tanhf_fast = [&](float c) -> float {
        return fmaf(2.f, __builtin_amdgcn_rcpf(1.f + __builtin_exp2f(c * TSC2)), -1.f);
    };

    // ---- register-stationary weights (per wave type), index-space prescale ----
    float sc0[4], sc1[4];         // L0: wi0s / b0s.  L1: (unused) / b1s.
    v8h wA[4][2], wB[4][2];       // L0: Whh0 / (unused).  L1: Wih1 / Whh1.
    #pragma unroll
    for (int tau = 0; tau < 4; tau++) {
        float sc = (tau == 2) ? TG : SG;
        int n = tau * 64 + jj;
        if (isL0) {
            sc0[tau] = Wih0[n] * sc;
            sc1[tau] = (bih0[n] + bhh0[n]) * sc + IOFF;
        } else {
            sc1[tau] = (bih1[n] + bhh1[n]) * sc + IOFF;
        }
        #pragma unroll
        for (int kk = 0; kk < 2; kk++) {
            int k0 = kk * 32 + q * 8;   // B-frag: B[k0..k0+7][n=lane&15]
            v8h a, b;
            #pragma unroll
            for (int j = 0; j < 8; j++) {
                if (isL0) {
                    a[j] = (_Float16)(Whh0[n * HH + k0 + j] * sc);
                } else {
                    a[j] = (_Float16)(Wih1[n * HH + k0 + j] * sc);
                    b[j] = (_Float16)(Whh1[n * HH + k0 + j] * sc);
                }
            }
            wA[tau][kk] = a;
            if (!isL0) wB[tau][kk] = b;
        }
    }

    float cs[2] = {0.f, 0.f};   // c-state of my layer, rows mb, mb+1
    __syncthreads();

    // ---- prologue t=0: ha(0) from x(0) only (L0 waves) ----
    if (isL0) {
        #pragma unroll
        for (int s = 0; s < 2; s++) {
            int m = mb + s;
            float xv = xl[0][m];
            float iv = lutv(fmaf(xv, sc0[0], sc1[0]));
            float gv = fmaf(2.f, lutv(fmaf(xv, sc0[2], sc1[2])), -1.f);
            float ov = lutv(fmaf(xv, sc0[3], sc1[3]));
            cs[s] = iv * gv;
            hs[0][m][jj] = (_Float16)(ov * tanhf_fast(cs[s]));
        }
    }
    __syncthreads();

    // step k: reads buf[p] {ha(k-1), hb(k-2)}, writes buf[pw] {ha(k), hb(k-1)}
    auto step = [&](int k, int p, int pw, bool last) {
        v4f g0, g1, g2, g3;
        if (isL0) {
            v8h a0 = *(const v8h*)&hs[p][l7][q * 8];       // ha k 0-31
            v8h a1 = *(const v8h*)&hs[p][l7][32 + q * 8];  // ha k 32-63
            int kx = (k < TT) ? k : (TT - 1);
            v4f xv = *(const v4f*)&xl[kx][mr];
            v4f acc[4];
            #pragma unroll
            for (int tau = 0; tau < 4; tau++) {
                #pragma unroll
                for (int r = 0; r < 4; r++) acc[tau][r] = fmaf(xv[r], sc0[tau], sc1[tau]);
                acc[tau] = MFMA16(a0, wA[tau][0], acc[tau]);
                acc[tau] = MFMA16(a1, wA[tau][1], acc[tau]);
            }
            g0 = acc[0]; g1 = acc[1]; g2 = acc[2]; g3 = acc[3];
        } else {
            v8h a0 = *(const v8h*)&hs[p][l7][q * 8];
            v8h a1 = *(const v8h*)&hs[p][l7][32 + q * 8];
            v8h b0 = *(const v8h*)&hs[p][l7][64 + q * 8];  // hb k 0-31
            v8h b1 = *(const v8h*)&hs[p][l7][96 + q * 8];  // hb k 32-63
            v4f acc[4];
            #pragma unroll
            for (int tau = 0; tau < 4; tau++) {
                v4f bc = (v4f){sc1[tau], sc1[tau], sc1[tau], sc1[tau]};
                acc[tau] = MFMA16(a0, wA[tau][0], bc);     // bias as C operand
                acc[tau] = MFMA16(a1, wA[tau][1], acc[tau]);
                acc[tau] = MFMA16(b0, wB[tau][0], acc[tau]);
                acc[tau] = MFMA16(b1, wB[tau][1], acc[tau]);
            }
            g0 = acc[0]; g1 = acc[1]; g2 = acc[2]; g3 = acc[3];
        }

        // stage 1: all 8 sigma gathers issued together
        float svi[2], svf[2], svg[2], svo[2];
        #pragma unroll
        for (int s = 0; s < 2; s++) {
            svi[s] = lutv(g0[rr + s]);
            svf[s] = lutv(g1[rr + s]);
            svg[s] = lutv(g2[rr + s]);
            svo[s] = lutv(g3[rr + s]);
        }

        _Float16* wp = &hs[pw][mb][isL0 ? jj : (64 + jj)];

        // stage 2: c update, trans tanh, h write
        #pragma unroll
        for (int s = 0; s < 2; s++) {
            float gv = fmaf(2.f, svg[s], -1.f);
            cs[s] = fmaf(svf[s], cs[s], svi[s] * gv);
            float hv = svo[s] * tanhf_fast(cs[s]);
            wp[s * KST] = (_Float16)hv;
            if (last && !isL0) hbF[mb + s][jj] = hv;
        }
        __syncthreads();
    };

    // k = 1..256 (k=256 = layer-1 epilogue step; L0's ha output junk-but-finite)
    for (int k = 1; k <= TT; k += 2) {
        step(k,     0, 1, false);
        step(k + 1, 1, 0, (k + 1) == TT);
    }

    // ---- out[m][n] = hbF[m][:] . Wlin[n][:] + blin[n], 512 threads ----
    int m = tid >> 6;            // 0..7
    int n = tid & 63;
    float accO = blin[n];
    #pragma unroll 8
    for (int j = 0; j < HH; j++)
        accO = fmaf(hbF[m][j], Wlin[n * HH + j], accO);
    out[(row0 + m) * HH + n] = accO;
}

extern "C" void kernel_launch(void* const* d_in, const int* in_sizes, int n_in,
                              void* d_out, int out_size, void* d_ws, size_t ws_size,
                              hipStream_t stream) {
    const float* x    = (const float*)d_in[0];
    const float* Wih0 = (const float*)d_in[1];
    const float* Whh0 = (const float*)d_in[2];
    const float* bih0 = (const float*)d_in[3];
    const float* bhh0 = (const float*)d_in[4];
    const float* Wih1 = (const float*)d_in[5];
    const float* Whh1 = (const float*)d_in[6];
    const float* bih1 = (const float*)d_in[7];
    const float* bhh1 = (const float*)d_in[8];
    const float* Wlin = (const float*)d_in[9];
    const float* blin = (const float*)d_in[10];
    // 4096 rows / 8 per block = 512 blocks of 512 thr = 2 blocks/CU
    lstm2_kernel<<<512, 512, 0, stream>>>(x, Wih0, Whh0, bih0, bhh0,
                                          Wih1, Whh1, bih1, bhh1,
                                          Wlin, blin, (float*)d_out);
}